// Round 1
// baseline (453.120 us; speedup 1.0000x reference)
//
#include <hip/hip_runtime.h>

typedef float f32x4 __attribute__((ext_vector_type(4)));

#define FP8MAX 448.0f

// ---------------- amax ----------------

__global__ void zero_scalar(unsigned* p) {
    if (threadIdx.x == 0) *p = 0u;
}

__global__ void amax_kernel(const float4* __restrict__ x,
                            unsigned* __restrict__ amax_bits, int n4) {
    float m = 0.0f;
    int stride = gridDim.x * blockDim.x;
    for (int i = blockIdx.x * blockDim.x + threadIdx.x; i < n4; i += stride) {
        float4 v = x[i];
        m = fmaxf(m, fabsf(v.x));
        m = fmaxf(m, fabsf(v.y));
        m = fmaxf(m, fabsf(v.z));
        m = fmaxf(m, fabsf(v.w));
    }
#pragma unroll
    for (int off = 32; off > 0; off >>= 1)
        m = fmaxf(m, __shfl_down(m, off, 64));
    if ((threadIdx.x & 63) == 0)
        atomicMax(amax_bits, __float_as_uint(m));  // nonneg floats order as uints
}

// ---------------- quantize ----------------

__global__ void quant_act(const float4* __restrict__ x, unsigned* __restrict__ q,
                          const unsigned* __restrict__ amax_bits, int n4) {
    int i = blockIdx.x * blockDim.x + threadIdx.x;
    if (i >= n4) return;
    float amax = fmaxf(__uint_as_float(*amax_bits), 1e-12f);
    float s = FP8MAX / amax;  // same fp32 op order as reference
    float4 v = x[i];
    float a = fminf(fmaxf(v.x * s, -FP8MAX), FP8MAX);
    float b = fminf(fmaxf(v.y * s, -FP8MAX), FP8MAX);
    float c = fminf(fmaxf(v.z * s, -FP8MAX), FP8MAX);
    float d = fminf(fmaxf(v.w * s, -FP8MAX), FP8MAX);
    int r = __builtin_amdgcn_cvt_pk_fp8_f32(a, b, 0, false);  // bytes 0,1
    r = __builtin_amdgcn_cvt_pk_fp8_f32(c, d, r, true);       // bytes 2,3
    q[i] = (unsigned)r;
}

__global__ void quant_wgt(const float4* __restrict__ x, unsigned* __restrict__ q, int n4) {
    int i = blockIdx.x * blockDim.x + threadIdx.x;
    if (i >= n4) return;
    float4 v = x[i];  // already on the fp8 grid -> conversion is exact
    int r = __builtin_amdgcn_cvt_pk_fp8_f32(v.x, v.y, 0, false);
    r = __builtin_amdgcn_cvt_pk_fp8_f32(v.z, v.w, r, true);
    q[i] = (unsigned)r;
}

// ---------------- fp8 GEMM, C = A(MxK) * B(NxK)^T ----------------
// 128x128 tile, BK=64 bytes, 4 waves (2x2), each wave 4x4 accs of 16x16x32.
// LDS rows are 64 B (4 x 16B chunks); chunk c of row r is stored at position
// c ^ ((r>>1)&3) -- permutation applied on the GLOBAL source side so the LDS
// destination stays lane-contiguous (global_load_lds requirement). Reads undo
// the XOR; bank aliasing for ds_read_b64 lands at the 4-lane floor (free).

__global__ __launch_bounds__(256) void gemm_fp8_bt(
    const unsigned char* __restrict__ Aq,   // [M,K] fp8
    const unsigned char* __restrict__ Bq,   // [N,K] fp8
    const unsigned* __restrict__ amax_bits,
    const float* __restrict__ w_scale_p,
    const float* __restrict__ bias,
    float* __restrict__ C,
    int M, int N, int K) {
    __shared__ unsigned char lA[128 * 64];
    __shared__ unsigned char lB[128 * 64];

    const int tid = threadIdx.x;
    const int lane = tid & 63;
    const int wave = tid >> 6;

    const int bn = blockIdx.x;   // N fastest: A-tile reuse across bn in L2
    const int bm = blockIdx.y;
    const int row0 = bm * 128;
    const int col0 = bn * 128;

    const int wm = wave >> 1;
    const int wn = wave & 1;
    const int m_base = wm * 64;
    const int n_base = wn * 64;

    const int lane_lo = lane & 15;
    const int lane_hi = lane >> 4;
    const int sw = (lane_lo >> 1) & 3;   // == ((m>>1)&3) since m = lane_lo + 16*t
    const int h1 = lane_hi >> 1;
    const int o8 = (lane_hi & 1) * 8;

    f32x4 acc[4][4];
#pragma unroll
    for (int i = 0; i < 4; ++i)
#pragma unroll
        for (int j = 0; j < 4; ++j)
            acc[i][j] = (f32x4){0.f, 0.f, 0.f, 0.f};

    for (int k0 = 0; k0 < K; k0 += 64) {
#pragma unroll
        for (int it = 0; it < 2; ++it) {
            int chunk = tid + it * 256;          // 512 chunks of 16 B per tile
            int r = chunk >> 2;
            int cpos = chunk & 3;
            int csrc = cpos ^ ((r >> 1) & 3);    // source permutation
            const unsigned char* gA = Aq + (size_t)(row0 + r) * K + (k0 + csrc * 16);
            const unsigned char* gB = Bq + (size_t)(col0 + r) * K + (k0 + csrc * 16);
            __builtin_amdgcn_global_load_lds(
                (const __attribute__((address_space(1))) void*)gA,
                (__attribute__((address_space(3))) void*)(lA + chunk * 16), 16, 0, 0);
            __builtin_amdgcn_global_load_lds(
                (const __attribute__((address_space(1))) void*)gB,
                (__attribute__((address_space(3))) void*)(lB + chunk * 16), 16, 0, 0);
        }
        __syncthreads();

#pragma unroll
        for (int kk = 0; kk < 2; ++kk) {
            int koff = ((((kk << 1) | h1) ^ sw) << 4) + o8;
            long long af[4], bf[4];
#pragma unroll
            for (int i = 0; i < 4; ++i)
                af[i] = *(const long long*)(lA + (m_base + i * 16 + lane_lo) * 64 + koff);
#pragma unroll
            for (int j = 0; j < 4; ++j)
                bf[j] = *(const long long*)(lB + (n_base + j * 16 + lane_lo) * 64 + koff);
#pragma unroll
            for (int i = 0; i < 4; ++i)
#pragma unroll
                for (int j = 0; j < 4; ++j)
                    acc[i][j] = __builtin_amdgcn_mfma_f32_16x16x32_fp8_fp8(
                        af[i], bf[j], acc[i][j], 0, 0, 0);
        }
        __syncthreads();
    }

    // epilogue: out = acc * (1/scale * w_scale) + bias  (fp32 ops match reference)
    float amax = fmaxf(__uint_as_float(*amax_bits), 1e-12f);
    float scale = FP8MAX / amax;
    float a_scale = 1.0f / scale;
    float s = a_scale * w_scale_p[0];

#pragma unroll
    for (int i = 0; i < 4; ++i) {
#pragma unroll
        for (int j = 0; j < 4; ++j) {
            int col = col0 + n_base + j * 16 + lane_lo;       // C/D: col = lane&15
            float bv = bias[col];
#pragma unroll
            for (int r = 0; r < 4; ++r) {
                int row = row0 + m_base + i * 16 + lane_hi * 4 + r;  // row = quad*4+reg
                C[(size_t)row * N + col] = acc[i][j][r] * s + bv;
            }
        }
    }
}

// ---------------- launch ----------------

extern "C" void kernel_launch(void* const* d_in, const int* in_sizes, int n_in,
                              void* d_out, int out_size, void* d_ws, size_t ws_size,
                              hipStream_t stream) {
    const float* input   = (const float*)d_in[0];   // [M,K] f32
    const float* qweight = (const float*)d_in[1];   // [N,K] f32 (fp8-grid values)
    const float* w_scale = (const float*)d_in[2];   // scalar
    const float* bias    = (const float*)d_in[3];   // [N]
    float* out = (float*)d_out;

    const int N = in_sizes[3];
    const int K = in_sizes[1] / N;
    const int M = in_sizes[0] / K;

    unsigned* amax_bits = (unsigned*)d_ws;
    unsigned char* qA = (unsigned char*)d_ws + 256;
    unsigned char* qW = qA + (size_t)M * K;
    // ws usage: 256 + M*K + N*K bytes (~37.8 MB)

    hipLaunchKernelGGL(zero_scalar, dim3(1), dim3(64), 0, stream, amax_bits);

    const int n4a = (M / 4) * K;  // M*K/4
    hipLaunchKernelGGL(amax_kernel, dim3(2048), dim3(256), 0, stream,
                       (const float4*)input, amax_bits, n4a);

    hipLaunchKernelGGL(quant_act, dim3((n4a + 255) / 256), dim3(256), 0, stream,
                       (const float4*)input, (unsigned*)qA, amax_bits, n4a);

    const int n4w = (N / 4) * K;
    hipLaunchKernelGGL(quant_wgt, dim3((n4w + 255) / 256), dim3(256), 0, stream,
                       (const float4*)qweight, (unsigned*)qW, n4w);

    hipLaunchKernelGGL(gemm_fp8_bt, dim3(N / 128, M / 128), dim3(256), 0, stream,
                       qA, qW, amax_bits, w_scale, bias, out, M, N, K);
}

// Round 2
// 337.545 us; speedup vs baseline: 1.3424x; 1.3424x over previous
//
#include <hip/hip_runtime.h>

typedef float f32x4 __attribute__((ext_vector_type(4)));
typedef int   i32x4 __attribute__((ext_vector_type(4)));
typedef int   i32x8 __attribute__((ext_vector_type(8)));

#define FP8MAX 448.0f

// ---------------- amax: two-stage, NO atomics ----------------

__global__ void amax_part(const float4* __restrict__ x, float* __restrict__ partial, int n4) {
    float m = 0.0f;
    int stride = gridDim.x * blockDim.x;
    for (int i = blockIdx.x * blockDim.x + threadIdx.x; i < n4; i += stride) {
        float4 v = x[i];
        m = fmaxf(m, fmaxf(fmaxf(fabsf(v.x), fabsf(v.y)), fmaxf(fabsf(v.z), fabsf(v.w))));
    }
#pragma unroll
    for (int off = 32; off > 0; off >>= 1)
        m = fmaxf(m, __shfl_down(m, off, 64));
    __shared__ float ws[4];
    int wave = threadIdx.x >> 6;
    if ((threadIdx.x & 63) == 0) ws[wave] = m;
    __syncthreads();
    if (threadIdx.x == 0)
        partial[blockIdx.x] = fmaxf(fmaxf(ws[0], ws[1]), fmaxf(ws[2], ws[3]));
}

__global__ void amax_final(const float* __restrict__ partial, unsigned* __restrict__ amax_bits, int n) {
    float m = 0.0f;
    for (int i = threadIdx.x; i < n; i += blockDim.x) m = fmaxf(m, partial[i]);
#pragma unroll
    for (int off = 32; off > 0; off >>= 1)
        m = fmaxf(m, __shfl_down(m, off, 64));
    __shared__ float ws[4];
    int wave = threadIdx.x >> 6;
    if ((threadIdx.x & 63) == 0) ws[wave] = m;
    __syncthreads();
    if (threadIdx.x == 0)
        *amax_bits = __float_as_uint(fmaxf(fmaxf(ws[0], ws[1]), fmaxf(ws[2], ws[3])));
}

// ---------------- quantize (x4 vectorized, uint4 stores) ----------------

__device__ __forceinline__ unsigned pack_fp8_clip(float4 v, float s) {
    float a = fminf(fmaxf(v.x * s, -FP8MAX), FP8MAX);
    float b = fminf(fmaxf(v.y * s, -FP8MAX), FP8MAX);
    float c = fminf(fmaxf(v.z * s, -FP8MAX), FP8MAX);
    float d = fminf(fmaxf(v.w * s, -FP8MAX), FP8MAX);
    int r = __builtin_amdgcn_cvt_pk_fp8_f32(a, b, 0, false);
    r = __builtin_amdgcn_cvt_pk_fp8_f32(c, d, r, true);
    return (unsigned)r;
}

__global__ void quant_act(const float4* __restrict__ x, uint4* __restrict__ q,
                          const unsigned* __restrict__ amax_bits, int n16) {
    int i = blockIdx.x * blockDim.x + threadIdx.x;
    if (i >= n16) return;
    float amax = fmaxf(__uint_as_float(*amax_bits), 1e-12f);
    float s = FP8MAX / amax;  // same fp32 op order as reference
    uint4 r;
    r.x = pack_fp8_clip(x[i * 4 + 0], s);
    r.y = pack_fp8_clip(x[i * 4 + 1], s);
    r.z = pack_fp8_clip(x[i * 4 + 2], s);
    r.w = pack_fp8_clip(x[i * 4 + 3], s);
    q[i] = r;
}

__global__ void quant_wgt(const float4* __restrict__ x, uint4* __restrict__ q, int n16) {
    int i = blockIdx.x * blockDim.x + threadIdx.x;
    if (i >= n16) return;
    uint4 r;  // values already on fp8 grid -> conversion exact, no clip needed
    float4 v0 = x[i * 4 + 0], v1 = x[i * 4 + 1], v2 = x[i * 4 + 2], v3 = x[i * 4 + 3];
    int a = __builtin_amdgcn_cvt_pk_fp8_f32(v0.x, v0.y, 0, false);
    r.x = (unsigned)__builtin_amdgcn_cvt_pk_fp8_f32(v0.z, v0.w, a, true);
    a = __builtin_amdgcn_cvt_pk_fp8_f32(v1.x, v1.y, 0, false);
    r.y = (unsigned)__builtin_amdgcn_cvt_pk_fp8_f32(v1.z, v1.w, a, true);
    a = __builtin_amdgcn_cvt_pk_fp8_f32(v2.x, v2.y, 0, false);
    r.z = (unsigned)__builtin_amdgcn_cvt_pk_fp8_f32(v2.z, v2.w, a, true);
    a = __builtin_amdgcn_cvt_pk_fp8_f32(v3.x, v3.y, 0, false);
    r.w = (unsigned)__builtin_amdgcn_cvt_pk_fp8_f32(v3.z, v3.w, a, true);
    q[i] = r;
}

// ---------------- MX-fp8 GEMM, C = A(MxK) * B(NxK)^T ----------------
// 128x128 tile, BK=128 bytes, 4 waves (2x2), each wave 4x4 accs of
// 16x16x128 mfma_scale (scales = e8m0 127 = x1.0, numerically identical to
// plain fp8 MFMA). LDS rows are 128 B (8 x 16B chunks); logical chunk c of
// row r sits at position c ^ (r&7) -- permutation applied on the GLOBAL
// source side so the global_load_lds destination stays lane-contiguous.
// Read side: each bank-quad served by exactly 8 lanes = b128 floor.

__global__ __launch_bounds__(256) void gemm_fp8_mx(
    const unsigned char* __restrict__ Aq,   // [M,K] fp8
    const unsigned char* __restrict__ Bq,   // [N,K] fp8
    const unsigned* __restrict__ amax_bits,
    const float* __restrict__ w_scale_p,
    const float* __restrict__ bias,
    float* __restrict__ C,
    int M, int N, int K) {
    __shared__ unsigned char lA[128 * 128];
    __shared__ unsigned char lB[128 * 128];

    const int tid = threadIdx.x;
    const int lane = tid & 63;
    const int wave = tid >> 6;

    const int bn = blockIdx.x;   // N fastest: A-tile reuse across bn in L2
    const int bm = blockIdx.y;
    const int row0 = bm * 128;
    const int col0 = bn * 128;

    const int wm = wave >> 1;
    const int wn = wave & 1;
    const int m_base = wm * 64;
    const int n_base = wn * 64;

    const int lane_lo = lane & 15;
    const int h = lane >> 4;         // 0..3
    const int c0 = 2 * h;            // logical 16B chunk pair for this lane's k-range
    const int c1 = 2 * h + 1;

    f32x4 acc[4][4];
#pragma unroll
    for (int i = 0; i < 4; ++i)
#pragma unroll
        for (int j = 0; j < 4; ++j)
            acc[i][j] = (f32x4){0.f, 0.f, 0.f, 0.f};

    union frag8 { i32x8 v; i32x4 half[2]; };

    for (int k0 = 0; k0 < K; k0 += 128) {
#pragma unroll
        for (int it = 0; it < 4; ++it) {
            int chunk = tid + it * 256;          // 1024 chunks of 16 B per tile
            int r = chunk >> 3;
            int cpos = chunk & 7;
            int csrc = cpos ^ (r & 7);           // source-side permutation
            const unsigned char* gA = Aq + (size_t)(row0 + r) * K + (k0 + csrc * 16);
            const unsigned char* gB = Bq + (size_t)(col0 + r) * K + (k0 + csrc * 16);
            __builtin_amdgcn_global_load_lds(
                (const __attribute__((address_space(1))) void*)gA,
                (__attribute__((address_space(3))) void*)(lA + chunk * 16), 16, 0, 0);
            __builtin_amdgcn_global_load_lds(
                (const __attribute__((address_space(1))) void*)gB,
                (__attribute__((address_space(3))) void*)(lB + chunk * 16), 16, 0, 0);
        }
        __syncthreads();

        frag8 af[4], bf[4];
#pragma unroll
        for (int i = 0; i < 4; ++i) {
            int m = m_base + i * 16 + lane_lo;
            int p0 = c0 ^ (m & 7);
            int p1 = c1 ^ (m & 7);
            af[i].half[0] = *(const i32x4*)(lA + m * 128 + p0 * 16);
            af[i].half[1] = *(const i32x4*)(lA + m * 128 + p1 * 16);
        }
#pragma unroll
        for (int j = 0; j < 4; ++j) {
            int n = n_base + j * 16 + lane_lo;
            int p0 = c0 ^ (n & 7);
            int p1 = c1 ^ (n & 7);
            bf[j].half[0] = *(const i32x4*)(lB + n * 128 + p0 * 16);
            bf[j].half[1] = *(const i32x4*)(lB + n * 128 + p1 * 16);
        }
#pragma unroll
        for (int i = 0; i < 4; ++i)
#pragma unroll
            for (int j = 0; j < 4; ++j)
                acc[i][j] = __builtin_amdgcn_mfma_scale_f32_16x16x128_f8f6f4(
                    af[i].v, bf[j].v, acc[i][j],
                    0, 0,                 // cbsz=fp8, blgp=fp8
                    0, 0x7F7F7F7F,        // A scale opsel, e8m0 1.0
                    0, 0x7F7F7F7F);       // B scale opsel, e8m0 1.0
        __syncthreads();
    }

    // epilogue: out = acc * (1/scale * w_scale) + bias  (fp32 ops match reference)
    float amax = fmaxf(__uint_as_float(*amax_bits), 1e-12f);
    float scale = FP8MAX / amax;
    float a_scale = 1.0f / scale;
    float s = a_scale * w_scale_p[0];

    const int lane_hi = lane >> 4;
#pragma unroll
    for (int i = 0; i < 4; ++i) {
#pragma unroll
        for (int j = 0; j < 4; ++j) {
            int col = col0 + n_base + j * 16 + lane_lo;       // C/D: col = lane&15
            float bv = bias[col];
#pragma unroll
            for (int r = 0; r < 4; ++r) {
                int row = row0 + m_base + i * 16 + lane_hi * 4 + r;  // row = quad*4+reg
                C[(size_t)row * N + col] = acc[i][j][r] * s + bv;
            }
        }
    }
}

// ---------------- launch ----------------

extern "C" void kernel_launch(void* const* d_in, const int* in_sizes, int n_in,
                              void* d_out, int out_size, void* d_ws, size_t ws_size,
                              hipStream_t stream) {
    const float* input   = (const float*)d_in[0];   // [M,K] f32
    const float* qweight = (const float*)d_in[1];   // [N,K] f32 (fp8-grid values)
    const float* w_scale = (const float*)d_in[2];   // scalar
    const float* bias    = (const float*)d_in[3];   // [N]
    float* out = (float*)d_out;

    const int N = in_sizes[3];
    const int K = in_sizes[1] / N;
    const int M = in_sizes[0] / K;

    unsigned* amax_bits = (unsigned*)d_ws;
    float* partial = (float*)((char*)d_ws + 256);               // 2048 floats
    unsigned char* qA = (unsigned char*)d_ws + 16384;
    unsigned char* qW = qA + (size_t)M * K;
    // ws usage: 16384 + M*K + N*K bytes (~37.8 MB)

    const int AMAX_BLOCKS = 2048;
    const int n4a = (M / 4) * K;
    hipLaunchKernelGGL(amax_part, dim3(AMAX_BLOCKS), dim3(256), 0, stream,
                       (const float4*)input, partial, n4a);
    hipLaunchKernelGGL(amax_final, dim3(1), dim3(256), 0, stream,
                       partial, amax_bits, AMAX_BLOCKS);

    const int n16a = n4a / 4;
    hipLaunchKernelGGL(quant_act, dim3((n16a + 255) / 256), dim3(256), 0, stream,
                       (const float4*)input, (uint4*)qA, amax_bits, n16a);

    const int n16w = (N / 4) * K / 4;
    hipLaunchKernelGGL(quant_wgt, dim3((n16w + 255) / 256), dim3(256), 0, stream,
                       (const float4*)qweight, (uint4*)qW, n16w);

    hipLaunchKernelGGL(gemm_fp8_mx, dim3(N / 128, M / 128), dim3(256), 0, stream,
                       qA, qW, amax_bits, w_scale, bias, out, M, N, K);
}

// Round 3
// 329.769 us; speedup vs baseline: 1.3741x; 1.0236x over previous
//
#include <hip/hip_runtime.h>

typedef float f32x4 __attribute__((ext_vector_type(4)));
typedef int   i32x4 __attribute__((ext_vector_type(4)));
typedef int   i32x8 __attribute__((ext_vector_type(8)));

#define FP8MAX 448.0f
#define AMAX_BLOCKS 2048
#define WQ_BLOCKS 512

// ---------------- fused: amax partials (blocks 0..2047) + weight quant (blocks 2048..2559) ----------------

__device__ __forceinline__ unsigned pack_fp8_exact(float4 v) {
    int r = __builtin_amdgcn_cvt_pk_fp8_f32(v.x, v.y, 0, false);
    return (unsigned)__builtin_amdgcn_cvt_pk_fp8_f32(v.z, v.w, r, true);
}

__global__ __launch_bounds__(256) void amax_and_wquant(
    const float4* __restrict__ x, float* __restrict__ partial, int n4,
    const float4* __restrict__ w, uint4* __restrict__ qw, int n16w) {
    if (blockIdx.x < AMAX_BLOCKS) {
        // grid-stride abs-max over the activation, two accumulators to break the chain
        float m0 = 0.0f, m1 = 0.0f;
        int stride = AMAX_BLOCKS * 256;
        int i = blockIdx.x * 256 + threadIdx.x;
        for (; i + stride < n4; i += 2 * stride) {
            float4 a = x[i];
            float4 b = x[i + stride];
            m0 = fmaxf(m0, fmaxf(fmaxf(fabsf(a.x), fabsf(a.y)), fmaxf(fabsf(a.z), fabsf(a.w))));
            m1 = fmaxf(m1, fmaxf(fmaxf(fabsf(b.x), fabsf(b.y)), fmaxf(fabsf(b.z), fabsf(b.w))));
        }
        if (i < n4) {
            float4 a = x[i];
            m0 = fmaxf(m0, fmaxf(fmaxf(fabsf(a.x), fabsf(a.y)), fmaxf(fabsf(a.z), fabsf(a.w))));
        }
        float m = fmaxf(m0, m1);
#pragma unroll
        for (int off = 32; off > 0; off >>= 1)
            m = fmaxf(m, __shfl_down(m, off, 64));
        __shared__ float ws[4];
        if ((threadIdx.x & 63) == 0) ws[threadIdx.x >> 6] = m;
        __syncthreads();
        if (threadIdx.x == 0)
            partial[blockIdx.x] = fmaxf(fmaxf(ws[0], ws[1]), fmaxf(ws[2], ws[3]));
    } else {
        // weight quantization: values already on the fp8 grid -> conversion exact
        int stride = WQ_BLOCKS * 256;
        for (int i = (blockIdx.x - AMAX_BLOCKS) * 256 + threadIdx.x; i < n16w; i += stride) {
            uint4 r;
            r.x = pack_fp8_exact(w[i * 4 + 0]);
            r.y = pack_fp8_exact(w[i * 4 + 1]);
            r.z = pack_fp8_exact(w[i * 4 + 2]);
            r.w = pack_fp8_exact(w[i * 4 + 3]);
            qw[i] = r;
        }
    }
}

// ---------------- act quant; every block self-reduces the partials (no extra kernel) ----------------

__device__ __forceinline__ float reduce_partials(const float* __restrict__ partial) {
    // all blocks compute the identical max over AMAX_BLOCKS entries (L2-warm)
    float m = 0.0f;
#pragma unroll
    for (int j = 0; j < AMAX_BLOCKS / 256; ++j)
        m = fmaxf(m, partial[threadIdx.x + j * 256]);
#pragma unroll
    for (int off = 32; off > 0; off >>= 1)
        m = fmaxf(m, __shfl_down(m, off, 64));
    __shared__ float ws[4];
    if ((threadIdx.x & 63) == 0) ws[threadIdx.x >> 6] = m;
    __syncthreads();
    return fmaxf(fmaxf(ws[0], ws[1]), fmaxf(ws[2], ws[3]));
}

__device__ __forceinline__ unsigned pack_fp8_clip(float4 v, float s) {
    float a = fminf(fmaxf(v.x * s, -FP8MAX), FP8MAX);
    float b = fminf(fmaxf(v.y * s, -FP8MAX), FP8MAX);
    float c = fminf(fmaxf(v.z * s, -FP8MAX), FP8MAX);
    float d = fminf(fmaxf(v.w * s, -FP8MAX), FP8MAX);
    int r = __builtin_amdgcn_cvt_pk_fp8_f32(a, b, 0, false);
    r = __builtin_amdgcn_cvt_pk_fp8_f32(c, d, r, true);
    return (unsigned)r;
}

__global__ __launch_bounds__(256) void quant_act(
    const float4* __restrict__ x, uint4* __restrict__ q,
    const float* __restrict__ partial, unsigned* __restrict__ amax_bits, int n16) {
    float amax = fmaxf(reduce_partials(partial), 1e-12f);
    if (blockIdx.x == 0 && threadIdx.x == 0)
        *amax_bits = __float_as_uint(amax);          // publish for the GEMM epilogue
    float s = FP8MAX / amax;                          // same fp32 op order as reference
    int i = blockIdx.x * blockDim.x + threadIdx.x;
    if (i >= n16) return;
    uint4 r;
    r.x = pack_fp8_clip(x[i * 4 + 0], s);
    r.y = pack_fp8_clip(x[i * 4 + 1], s);
    r.z = pack_fp8_clip(x[i * 4 + 2], s);
    r.w = pack_fp8_clip(x[i * 4 + 3], s);
    q[i] = r;
}

// ---------------- MX-fp8 GEMM, C = A(MxK) * B(NxK)^T ----------------
// 128x128 tile, BK=128 bytes, 4 waves (2x2), each wave 4x4 accs of
// 16x16x128 mfma_scale (scales = e8m0 127 = x1.0, numerically identical to
// plain fp8 MFMA). LDS rows are 128 B (8 x 16B chunks); logical chunk c of
// row r sits at position c ^ (r&7) -- permutation applied on the GLOBAL
// source side so the global_load_lds destination stays lane-contiguous.

__global__ __launch_bounds__(256) void gemm_fp8_mx(
    const unsigned char* __restrict__ Aq,   // [M,K] fp8
    const unsigned char* __restrict__ Bq,   // [N,K] fp8
    const unsigned* __restrict__ amax_bits,
    const float* __restrict__ w_scale_p,
    const float* __restrict__ bias,
    float* __restrict__ C,
    int M, int N, int K) {
    __shared__ unsigned char lA[128 * 128];
    __shared__ unsigned char lB[128 * 128];

    const int tid = threadIdx.x;
    const int lane = tid & 63;
    const int wave = tid >> 6;

    const int bn = blockIdx.x;   // N fastest: A-tile reuse across bn in L2
    const int bm = blockIdx.y;
    const int row0 = bm * 128;
    const int col0 = bn * 128;

    const int wm = wave >> 1;
    const int wn = wave & 1;
    const int m_base = wm * 64;
    const int n_base = wn * 64;

    const int lane_lo = lane & 15;
    const int h = lane >> 4;         // 0..3
    const int c0 = 2 * h;            // logical 16B chunk pair for this lane's k-range
    const int c1 = 2 * h + 1;

    f32x4 acc[4][4];
#pragma unroll
    for (int i = 0; i < 4; ++i)
#pragma unroll
        for (int j = 0; j < 4; ++j)
            acc[i][j] = (f32x4){0.f, 0.f, 0.f, 0.f};

    union frag8 { i32x8 v; i32x4 half[2]; };

    for (int k0 = 0; k0 < K; k0 += 128) {
#pragma unroll
        for (int it = 0; it < 4; ++it) {
            int chunk = tid + it * 256;          // 1024 chunks of 16 B per tile
            int r = chunk >> 3;
            int cpos = chunk & 7;
            int csrc = cpos ^ (r & 7);           // source-side permutation
            const unsigned char* gA = Aq + (size_t)(row0 + r) * K + (k0 + csrc * 16);
            const unsigned char* gB = Bq + (size_t)(col0 + r) * K + (k0 + csrc * 16);
            __builtin_amdgcn_global_load_lds(
                (const __attribute__((address_space(1))) void*)gA,
                (__attribute__((address_space(3))) void*)(lA + chunk * 16), 16, 0, 0);
            __builtin_amdgcn_global_load_lds(
                (const __attribute__((address_space(1))) void*)gB,
                (__attribute__((address_space(3))) void*)(lB + chunk * 16), 16, 0, 0);
        }
        __syncthreads();

        frag8 af[4], bf[4];
#pragma unroll
        for (int i = 0; i < 4; ++i) {
            int m = m_base + i * 16 + lane_lo;
            int p0 = c0 ^ (m & 7);
            int p1 = c1 ^ (m & 7);
            af[i].half[0] = *(const i32x4*)(lA + m * 128 + p0 * 16);
            af[i].half[1] = *(const i32x4*)(lA + m * 128 + p1 * 16);
        }
#pragma unroll
        for (int j = 0; j < 4; ++j) {
            int n = n_base + j * 16 + lane_lo;
            int p0 = c0 ^ (n & 7);
            int p1 = c1 ^ (n & 7);
            bf[j].half[0] = *(const i32x4*)(lB + n * 128 + p0 * 16);
            bf[j].half[1] = *(const i32x4*)(lB + n * 128 + p1 * 16);
        }
#pragma unroll
        for (int i = 0; i < 4; ++i)
#pragma unroll
            for (int j = 0; j < 4; ++j)
                acc[i][j] = __builtin_amdgcn_mfma_scale_f32_16x16x128_f8f6f4(
                    af[i].v, bf[j].v, acc[i][j],
                    0, 0,                 // cbsz=fp8, blgp=fp8
                    0, 0x7F7F7F7F,        // A scale opsel, e8m0 1.0
                    0, 0x7F7F7F7F);       // B scale opsel, e8m0 1.0
        __syncthreads();
    }

    // epilogue: out = acc * (1/scale * w_scale) + bias  (fp32 ops match reference)
    float amax = fmaxf(__uint_as_float(*amax_bits), 1e-12f);
    float scale = FP8MAX / amax;
    float a_scale = 1.0f / scale;
    float s = a_scale * w_scale_p[0];

    const int lane_hi = lane >> 4;
#pragma unroll
    for (int i = 0; i < 4; ++i) {
#pragma unroll
        for (int j = 0; j < 4; ++j) {
            int col = col0 + n_base + j * 16 + lane_lo;       // C/D: col = lane&15
            float bv = bias[col];
#pragma unroll
            for (int r = 0; r < 4; ++r) {
                int row = row0 + m_base + i * 16 + lane_hi * 4 + r;  // row = quad*4+reg
                C[(size_t)row * N + col] = acc[i][j][r] * s + bv;
            }
        }
    }
}

// ---------------- launch: 3 kernels total ----------------

extern "C" void kernel_launch(void* const* d_in, const int* in_sizes, int n_in,
                              void* d_out, int out_size, void* d_ws, size_t ws_size,
                              hipStream_t stream) {
    const float* input   = (const float*)d_in[0];   // [M,K] f32
    const float* qweight = (const float*)d_in[1];   // [N,K] f32 (fp8-grid values)
    const float* w_scale = (const float*)d_in[2];   // scalar
    const float* bias    = (const float*)d_in[3];   // [N]
    float* out = (float*)d_out;

    const int N = in_sizes[3];
    const int K = in_sizes[1] / N;
    const int M = in_sizes[0] / K;

    unsigned* amax_bits = (unsigned*)d_ws;
    float* partial = (float*)((char*)d_ws + 256);               // AMAX_BLOCKS floats
    unsigned char* qA = (unsigned char*)d_ws + 16384;
    unsigned char* qW = qA + (size_t)M * K;
    // ws usage: 16384 + M*K + N*K bytes (~37.8 MB)

    const int n4a  = (M / 4) * K;
    const int n16w = (N / 4) * K / 4;
    hipLaunchKernelGGL(amax_and_wquant, dim3(AMAX_BLOCKS + WQ_BLOCKS), dim3(256), 0, stream,
                       (const float4*)input, partial, n4a,
                       (const float4*)qweight, (uint4*)qW, n16w);

    const int n16a = n4a / 4;
    hipLaunchKernelGGL(quant_act, dim3((n16a + 255) / 256), dim3(256), 0, stream,
                       (const float4*)input, (uint4*)qA, partial, amax_bits, n16a);

    hipLaunchKernelGGL(gemm_fp8_mx, dim3(N / 128, M / 128), dim3(256), 0, stream,
                       qA, qW, amax_bits, w_scale, bias, out, M, N, K);
}